// Round 4
// baseline (127.493 us; speedup 1.0000x reference)
//
#include <hip/hip_runtime.h>
#include <hip/hip_bf16.h>
#include <math.h>

#define NN 4096
#define DD 1024
#define NCLS 128
#define TAU 0.5f
#define EPSV 1e-8f

typedef __bf16 bf16;
typedef __bf16 bf16x8 __attribute__((ext_vector_type(8)));
typedef __bf16 bf16x4 __attribute__((ext_vector_type(4)));
typedef float f32x4 __attribute__((ext_vector_type(4)));

__device__ __forceinline__ void gl2lds16(const void* g, void* l) {
    __builtin_amdgcn_global_load_lds(
        (const __attribute__((address_space(1))) void*)g,
        (__attribute__((address_space(3))) void*)l,
        16, 0, 0);
}

// K1: per-row L2 norm -> normalized bf16 copy; zero rsum. Block 0 additionally
// computes class stats (cnt, min-idx, 2nd-min-idx) and zeroes out.
__global__ __launch_bounds__(256) void k_prep(const float* __restrict__ X,
                                              bf16* __restrict__ Xn,
                                              float* __restrict__ rsum,
                                              const int* __restrict__ y,
                                              int* __restrict__ cnt,
                                              int* __restrict__ mn1,
                                              int* __restrict__ mn2,
                                              float* __restrict__ out) {
    int w = threadIdx.x >> 6, lane = threadIdx.x & 63;
    int row = blockIdx.x * 4 + w;
    const float* xr = X + (size_t)row * DD;
    float4 v[4];
    float ss = 0.f;
#pragma unroll
    for (int c = 0; c < 4; ++c) {
        v[c] = *(const float4*)(xr + c * 256 + lane * 4);
        ss += v[c].x * v[c].x + v[c].y * v[c].y + v[c].z * v[c].z + v[c].w * v[c].w;
    }
#pragma unroll
    for (int m = 1; m < 64; m <<= 1) ss += __shfl_xor(ss, m, 64);
    float rn = 1.f / fmaxf(sqrtf(ss), EPSV);
    if (lane == 0) rsum[row] = 0.f;
#pragma unroll
    for (int c = 0; c < 4; ++c) {
        bf16x4 o;
        o.x = (bf16)(v[c].x * rn);
        o.y = (bf16)(v[c].y * rn);
        o.z = (bf16)(v[c].z * rn);
        o.w = (bf16)(v[c].w * rn);
        *(bf16x4*)(Xn + (size_t)row * DD + c * 256 + lane * 4) = o;
    }

    if (blockIdx.x == 0) {
        __shared__ int sc[NCLS], s1[NCLS], s2[NCLS];
        int t = threadIdx.x;
        if (t < NCLS) { sc[t] = 0; s1[t] = 0x7fffffff; s2[t] = 0x7fffffff; }
        __syncthreads();
        int yv[16];
#pragma unroll
        for (int k = 0; k < 16; ++k) {
            int i = k * 256 + t;
            yv[k] = y[i];
            atomicAdd(&sc[yv[k]], 1);
            atomicMin(&s1[yv[k]], i);
        }
        __syncthreads();
#pragma unroll
        for (int k = 0; k < 16; ++k) {
            int i = k * 256 + t;
            if (s1[yv[k]] != i) atomicMin(&s2[yv[k]], i);
        }
        __syncthreads();
        if (t < NCLS) { cnt[t] = sc[t]; mn1[t] = s1[t]; mn2[t] = s2[t]; }
        if (t == 0) out[0] = 0.f;
    }
}

// K2: upper-triangle 128x128-tile bf16 MFMA gram, BK=64, fused exp/mask epilogue.
// Off-diagonal tiles contribute to rowsum via row-reduce AND col-reduce (symmetry).
__global__ __launch_bounds__(256) void k_gemm(const bf16* __restrict__ Xn,
                                              const int* __restrict__ y,
                                              float* __restrict__ rowsum) {
    __shared__ __align__(16) bf16 As[128 * 64];
    __shared__ __align__(16) bf16 Bs[128 * 64];
    __shared__ int yA[128], yB[128];

    // decode linear block id -> (bi, bj), bi <= bj
    int id = blockIdx.x;
    float ff = sqrtf((float)(8 * id + 1));
    int bj = (int)((ff - 1.f) * 0.5f);
    if (bj * (bj + 1) / 2 > id) bj--;
    if ((bj + 1) * (bj + 2) / 2 <= id) bj++;
    int bi = id - bj * (bj + 1) / 2;
    const int rowA0 = bi * 128;
    const int rowB0 = bj * 128;
    const bool diag = (bi == bj);

    const int tid = threadIdx.x;
    if (tid < 128) yA[tid] = y[rowA0 + tid];
    else           yB[tid - 128] = y[rowB0 + tid - 128];

    const int lane = tid & 63;
    const int w = tid >> 6;
    const int wm = w & 1, wn = w >> 1;     // 2x2 waves -> each wave 64x64
    const int lr = lane >> 4, lc = lane & 15;

    f32x4 acc[4][4];
#pragma unroll
    for (int i = 0; i < 4; ++i)
#pragma unroll
        for (int j = 0; j < 4; ++j) acc[i][j] = (f32x4){0.f, 0.f, 0.f, 0.f};

    // staging: slot s in [0,1024): row=s>>3, g=s&7; slot g holds k-group g^(row&7)
    const bf16* gA[4]; const bf16* gB[4];
    bf16* lA[4]; bf16* lB[4];
#pragma unroll
    for (int q = 0; q < 4; ++q) {
        int s = q * 256 + tid;
        int row = s >> 3;
        int kg = (s & 7) ^ (row & 7);
        gA[q] = Xn + (size_t)(rowA0 + row) * DD + kg * 8;
        gB[q] = Xn + (size_t)(rowB0 + row) * DD + kg * 8;
        lA[q] = As + s * 8;
        lB[q] = Bs + s * 8;
    }

    const int sw = lc & 7;   // read-side slot swizzle

    for (int k0 = 0; k0 < DD; k0 += 64) {
        __syncthreads();
#pragma unroll
        for (int q = 0; q < 4; ++q) {
            gl2lds16(gA[q] + k0, lA[q]);
            gl2lds16(gB[q] + k0, lB[q]);
        }
        __syncthreads();

#pragma unroll
        for (int ks = 0; ks < 2; ++ks) {
            bf16x8 af[4], bfr[4];
            int slot = (ks * 4 + lr) ^ sw;
#pragma unroll
            for (int mt = 0; mt < 4; ++mt)
                af[mt] = *(const bf16x8*)(As + (wm * 64 + mt * 16 + lc) * 64 + slot * 8);
#pragma unroll
            for (int nt = 0; nt < 4; ++nt)
                bfr[nt] = *(const bf16x8*)(Bs + (wn * 64 + nt * 16 + lc) * 64 + slot * 8);
#pragma unroll
            for (int mt = 0; mt < 4; ++mt)
#pragma unroll
                for (int nt = 0; nt < 4; ++nt)
                    acc[mt][nt] = __builtin_amdgcn_mfma_f32_16x16x32_bf16(
                        af[mt], bfr[nt], acc[mt][nt], 0, 0, 0);
        }
    }

    // Epilogue: S=(c+1)*0.25; mask same-class (incl. diagonal); row+col exp-sums.
    int ycol[4];
#pragma unroll
    for (int nt = 0; nt < 4; ++nt) ycol[nt] = yB[wn * 64 + nt * 16 + lc];
    float colacc[4] = {0.f, 0.f, 0.f, 0.f};
#pragma unroll
    for (int mt = 0; mt < 4; ++mt) {
#pragma unroll
        for (int rr = 0; rr < 4; ++rr) {
            int rloc = wm * 64 + mt * 16 + lr * 4 + rr;  // C row = (lane>>4)*4+reg
            int yrow = yA[rloc];
            float s = 0.f;
#pragma unroll
            for (int nt = 0; nt < 4; ++nt) {
                float Sv = (acc[mt][nt][rr] + 1.f) * (0.5f * TAU);
                float e = (ycol[nt] != yrow) ? __expf(Sv) : 0.f;
                s += e;
                colacc[nt] += e;
            }
            s += __shfl_xor(s, 1, 16);
            s += __shfl_xor(s, 2, 16);
            s += __shfl_xor(s, 4, 16);
            s += __shfl_xor(s, 8, 16);
            if (lc == 0) atomicAdd(&rowsum[rowA0 + rloc], s);
        }
    }
    if (!diag) {
#pragma unroll
        for (int nt = 0; nt < 4; ++nt) {
            float cs = colacc[nt];
            cs += __shfl_xor(cs, 16, 64);
            cs += __shfl_xor(cs, 32, 64);
            if (lane < 16) atomicAdd(&rowsum[rowB0 + wn * 64 + nt * 16 + lane], cs);
        }
    }
}

// K3: fused posval + finalize. One wave per row:
// pv = (dot(Xn_i, Xn_firstpos)+1)*0.25 ; contrib = log(rowsum + exp(pv) + (N-2+cnt)) - pv
// block-reduce contribs, atomicAdd into out.
__global__ __launch_bounds__(256) void k_tail(const bf16* __restrict__ Xn,
                                              const int* __restrict__ y,
                                              const int* __restrict__ cnt,
                                              const int* __restrict__ mn1,
                                              const int* __restrict__ mn2,
                                              const float* __restrict__ rowsum,
                                              float* __restrict__ out) {
    int w = threadIdx.x >> 6, lane = threadIdx.x & 63;
    int i = blockIdx.x * 4 + w;
    int c = y[i];
    int cc = cnt[c];
    float pv = 0.f;
    if (cc >= 2) {
        int fp = (mn1[c] == i) ? mn2[c] : mn1[c];
        const bf16* xi = Xn + (size_t)i * DD;
        const bf16* xf = Xn + (size_t)fp * DD;
        float dot = 0.f;
#pragma unroll
        for (int q = 0; q < 2; ++q) {
            bf16x8 a = *(const bf16x8*)(xi + q * 512 + lane * 8);
            bf16x8 b = *(const bf16x8*)(xf + q * 512 + lane * 8);
#pragma unroll
            for (int e = 0; e < 8; ++e) dot += (float)a[e] * (float)b[e];
        }
#pragma unroll
        for (int m = 1; m < 64; m <<= 1) dot += __shfl_xor(dot, m, 64);
        pv = (dot + 1.f) * (0.5f * TAU);
    }
    float contrib = logf(rowsum[i] + __expf(pv) + (float)(NN - 2 + cc)) - pv;
    __shared__ float wsum[4];
    if (lane == 0) wsum[w] = contrib;
    __syncthreads();
    if (threadIdx.x == 0)
        atomicAdd(out, (wsum[0] + wsum[1] + wsum[2] + wsum[3]) * (1.f / (float)NN));
}

extern "C" void kernel_launch(void* const* d_in, const int* in_sizes, int n_in,
                              void* d_out, int out_size, void* d_ws, size_t ws_size,
                              hipStream_t stream) {
    const float* X = (const float*)d_in[0];
    const int* y = (const int*)d_in[1];
    float* out = (float*)d_out;

    char* ws = (char*)d_ws;
    bf16* Xn    = (bf16*)ws;                                  // 8 MB
    float* rsum = (float*)(ws + 8 * 1024 * 1024);             // 16 KB
    int* cnt    = (int*)(ws + 8 * 1024 * 1024 + 16 * 1024);
    int* mn1    = (int*)(ws + 8 * 1024 * 1024 + 16 * 1024 + 512);
    int* mn2    = (int*)(ws + 8 * 1024 * 1024 + 16 * 1024 + 1024);

    k_prep<<<dim3(NN / 4), 256, 0, stream>>>(X, Xn, rsum, y, cnt, mn1, mn2, out);
    k_gemm<<<dim3(528), 256, 0, stream>>>(Xn, y, rsum);
    k_tail<<<dim3(NN / 4), 256, 0, stream>>>(Xn, y, cnt, mn1, mn2, rsum, out);
}

// Round 5
// 126.061 us; speedup vs baseline: 1.0114x; 1.0114x over previous
//
#include <hip/hip_runtime.h>
#include <hip/hip_bf16.h>
#include <math.h>

#define NN 4096
#define DD 1024
#define NCLS 128
#define TAU 0.5f
#define EPSV 1e-8f

typedef __bf16 bf16;
typedef __bf16 bf16x8 __attribute__((ext_vector_type(8)));
typedef __bf16 bf16x4 __attribute__((ext_vector_type(4)));
typedef float f32x4 __attribute__((ext_vector_type(4)));

__device__ __forceinline__ void gl2lds16(const void* g, void* l) {
    __builtin_amdgcn_global_load_lds(
        (const __attribute__((address_space(1))) void*)g,
        (__attribute__((address_space(3))) void*)l,
        16, 0, 0);
}

// K1: per-row L2 norm -> normalized bf16 copy; zero rsum. Block 0 additionally
// computes class stats (cnt, min-idx, 2nd-min-idx) and zeroes out.
__global__ __launch_bounds__(256) void k_prep(const float* __restrict__ X,
                                              bf16* __restrict__ Xn,
                                              float* __restrict__ rsum,
                                              const int* __restrict__ y,
                                              int* __restrict__ cnt,
                                              int* __restrict__ mn1,
                                              int* __restrict__ mn2,
                                              float* __restrict__ out) {
    int w = threadIdx.x >> 6, lane = threadIdx.x & 63;
    int row = blockIdx.x * 4 + w;
    const float* xr = X + (size_t)row * DD;
    float4 v[4];
    float ss = 0.f;
#pragma unroll
    for (int c = 0; c < 4; ++c) {
        v[c] = *(const float4*)(xr + c * 256 + lane * 4);
        ss += v[c].x * v[c].x + v[c].y * v[c].y + v[c].z * v[c].z + v[c].w * v[c].w;
    }
#pragma unroll
    for (int m = 1; m < 64; m <<= 1) ss += __shfl_xor(ss, m, 64);
    float rn = 1.f / fmaxf(sqrtf(ss), EPSV);
    if (lane == 0) rsum[row] = 0.f;
#pragma unroll
    for (int c = 0; c < 4; ++c) {
        bf16x4 o;
        o.x = (bf16)(v[c].x * rn);
        o.y = (bf16)(v[c].y * rn);
        o.z = (bf16)(v[c].z * rn);
        o.w = (bf16)(v[c].w * rn);
        *(bf16x4*)(Xn + (size_t)row * DD + c * 256 + lane * 4) = o;
    }

    if (blockIdx.x == 0) {
        __shared__ int sc[NCLS], s1[NCLS], s2[NCLS];
        int t = threadIdx.x;
        if (t < NCLS) { sc[t] = 0; s1[t] = 0x7fffffff; s2[t] = 0x7fffffff; }
        __syncthreads();
        int yv[16];
#pragma unroll
        for (int k = 0; k < 16; ++k) {
            int i = k * 256 + t;
            yv[k] = y[i];
            atomicAdd(&sc[yv[k]], 1);
            atomicMin(&s1[yv[k]], i);
        }
        __syncthreads();
#pragma unroll
        for (int k = 0; k < 16; ++k) {
            int i = k * 256 + t;
            if (s1[yv[k]] != i) atomicMin(&s2[yv[k]], i);
        }
        __syncthreads();
        if (t < NCLS) { cnt[t] = sc[t]; mn1[t] = s1[t]; mn2[t] = s2[t]; }
        if (t == 0) out[0] = 0.f;
    }
}

// K2: upper-triangle gram, 128x64 half-tiles, 2 waves/block, BK=32.
// blockIdx.x = tile*2 + half. Off-diag tiles also col-reduce (symmetry).
__global__ __launch_bounds__(128) void k_gemm(const bf16* __restrict__ Xn,
                                              const int* __restrict__ y,
                                              float* __restrict__ rowsum) {
    __shared__ __align__(16) bf16 As[128 * 32];
    __shared__ __align__(16) bf16 Bs[64 * 32];
    __shared__ int yA[128], yB[64];

    // decode: tile id -> (bi, bj) with bi <= bj; half h selects 64-col slab
    int t = blockIdx.x >> 1;
    int h = blockIdx.x & 1;
    float ff = sqrtf((float)(8 * t + 1));
    int bj = (int)((ff - 1.f) * 0.5f);
    if (bj * (bj + 1) / 2 > t) bj--;
    if ((bj + 1) * (bj + 2) / 2 <= t) bj++;
    int bi = t - bj * (bj + 1) / 2;
    const int rowA0 = bi * 128;
    const int colB0 = bj * 128 + h * 64;
    const bool diag = (bi == bj);

    const int tid = threadIdx.x;
    yA[tid] = y[rowA0 + tid];
    if (tid < 64) yB[tid] = y[colB0 + tid];

    const int lane = tid & 63;
    const int w = tid >> 6;              // 2 waves: rows w*64..w*64+63, all 64 cols
    const int lr = lane >> 4, lc = lane & 15;

    f32x4 acc[4][4];
#pragma unroll
    for (int i = 0; i < 4; ++i)
#pragma unroll
        for (int j = 0; j < 4; ++j) acc[i][j] = (f32x4){0.f, 0.f, 0.f, 0.f};

    // staging (BK=32): slot g of row r holds k-group g^((r>>1)&3)
    const bf16* gA[4]; bf16* lA[4];
#pragma unroll
    for (int q = 0; q < 4; ++q) {
        int s = q * 128 + tid;           // 512 slots for A (128 rows x 4 kgroups)
        int row = s >> 2, g = s & 3;
        int kg = g ^ ((row >> 1) & 3);
        gA[q] = Xn + (size_t)(rowA0 + row) * DD + kg * 8;
        lA[q] = As + s * 8;
    }
    const bf16* gB[2]; bf16* lB[2];
#pragma unroll
    for (int q = 0; q < 2; ++q) {
        int s = q * 128 + tid;           // 256 slots for B (64 rows x 4 kgroups)
        int row = s >> 2, g = s & 3;
        int kg = g ^ ((row >> 1) & 3);
        gB[q] = Xn + (size_t)(colB0 + row) * DD + kg * 8;
        lB[q] = Bs + s * 8;
    }

    const int sw = (lc >> 1) & 3;        // read-side slot swizzle
    const int slot = lr ^ sw;

    for (int k0 = 0; k0 < DD; k0 += 32) {
        __syncthreads();
#pragma unroll
        for (int q = 0; q < 4; ++q) gl2lds16(gA[q] + k0, lA[q]);
#pragma unroll
        for (int q = 0; q < 2; ++q) gl2lds16(gB[q] + k0, lB[q]);
        __syncthreads();

        bf16x8 af[4], bfr[4];
#pragma unroll
        for (int mt = 0; mt < 4; ++mt)
            af[mt] = *(const bf16x8*)(As + (w * 64 + mt * 16 + lc) * 32 + slot * 8);
#pragma unroll
        for (int nt = 0; nt < 4; ++nt)
            bfr[nt] = *(const bf16x8*)(Bs + (nt * 16 + lc) * 32 + slot * 8);
#pragma unroll
        for (int mt = 0; mt < 4; ++mt)
#pragma unroll
            for (int nt = 0; nt < 4; ++nt)
                acc[mt][nt] = __builtin_amdgcn_mfma_f32_16x16x32_bf16(
                    af[mt], bfr[nt], acc[mt][nt], 0, 0, 0);
    }

    // Epilogue: S=(c+1)*0.25; mask same-class; row + (off-diag) col exp-sums.
    int ycol[4];
#pragma unroll
    for (int nt = 0; nt < 4; ++nt) ycol[nt] = yB[nt * 16 + lc];
    float colacc[4] = {0.f, 0.f, 0.f, 0.f};
#pragma unroll
    for (int mt = 0; mt < 4; ++mt) {
#pragma unroll
        for (int rr = 0; rr < 4; ++rr) {
            int rloc = w * 64 + mt * 16 + lr * 4 + rr;   // C row = (lane>>4)*4+reg
            int yrow = yA[rloc];
            float s = 0.f;
#pragma unroll
            for (int nt = 0; nt < 4; ++nt) {
                float Sv = (acc[mt][nt][rr] + 1.f) * (0.5f * TAU);
                float e = (ycol[nt] != yrow) ? __expf(Sv) : 0.f;
                s += e;
                colacc[nt] += e;
            }
            s += __shfl_xor(s, 1, 16);
            s += __shfl_xor(s, 2, 16);
            s += __shfl_xor(s, 4, 16);
            s += __shfl_xor(s, 8, 16);
            if (lc == 0) atomicAdd(&rowsum[rowA0 + rloc], s);
        }
    }
    if (!diag) {
#pragma unroll
        for (int nt = 0; nt < 4; ++nt) {
            float cs = colacc[nt];
            cs += __shfl_xor(cs, 16, 64);
            cs += __shfl_xor(cs, 32, 64);
            if (lane < 16) atomicAdd(&rowsum[colB0 + nt * 16 + lane], cs);
        }
    }
}

// K3: fused posval + finalize. One wave per row.
__global__ __launch_bounds__(256) void k_tail(const bf16* __restrict__ Xn,
                                              const int* __restrict__ y,
                                              const int* __restrict__ cnt,
                                              const int* __restrict__ mn1,
                                              const int* __restrict__ mn2,
                                              const float* __restrict__ rowsum,
                                              float* __restrict__ out) {
    int w = threadIdx.x >> 6, lane = threadIdx.x & 63;
    int i = blockIdx.x * 4 + w;
    int c = y[i];
    int cc = cnt[c];
    float pv = 0.f;
    if (cc >= 2) {
        int fp = (mn1[c] == i) ? mn2[c] : mn1[c];
        const bf16* xi = Xn + (size_t)i * DD;
        const bf16* xf = Xn + (size_t)fp * DD;
        float dot = 0.f;
#pragma unroll
        for (int q = 0; q < 2; ++q) {
            bf16x8 a = *(const bf16x8*)(xi + q * 512 + lane * 8);
            bf16x8 b = *(const bf16x8*)(xf + q * 512 + lane * 8);
#pragma unroll
            for (int e = 0; e < 8; ++e) dot += (float)a[e] * (float)b[e];
        }
#pragma unroll
        for (int m = 1; m < 64; m <<= 1) dot += __shfl_xor(dot, m, 64);
        pv = (dot + 1.f) * (0.5f * TAU);
    }
    float contrib = logf(rowsum[i] + __expf(pv) + (float)(NN - 2 + cc)) - pv;
    __shared__ float wsum[4];
    if (lane == 0) wsum[w] = contrib;
    __syncthreads();
    if (threadIdx.x == 0)
        atomicAdd(out, (wsum[0] + wsum[1] + wsum[2] + wsum[3]) * (1.f / (float)NN));
}

extern "C" void kernel_launch(void* const* d_in, const int* in_sizes, int n_in,
                              void* d_out, int out_size, void* d_ws, size_t ws_size,
                              hipStream_t stream) {
    const float* X = (const float*)d_in[0];
    const int* y = (const int*)d_in[1];
    float* out = (float*)d_out;

    char* ws = (char*)d_ws;
    bf16* Xn    = (bf16*)ws;                                  // 8 MB
    float* rsum = (float*)(ws + 8 * 1024 * 1024);             // 16 KB
    int* cnt    = (int*)(ws + 8 * 1024 * 1024 + 16 * 1024);
    int* mn1    = (int*)(ws + 8 * 1024 * 1024 + 16 * 1024 + 512);
    int* mn2    = (int*)(ws + 8 * 1024 * 1024 + 16 * 1024 + 1024);

    k_prep<<<dim3(NN / 4), 256, 0, stream>>>(X, Xn, rsum, y, cnt, mn1, mn2, out);
    k_gemm<<<dim3(1056), 128, 0, stream>>>(Xn, y, rsum);
    k_tail<<<dim3(NN / 4), 256, 0, stream>>>(Xn, y, cnt, mn1, mn2, rsum, out);
}

// Round 6
// 122.273 us; speedup vs baseline: 1.0427x; 1.0310x over previous
//
#include <hip/hip_runtime.h>
#include <hip/hip_bf16.h>
#include <math.h>

#define NN 4096
#define DD 1024
#define NCLS 128
#define TAU 0.5f
#define EPSV 1e-8f

typedef __bf16 bf16;
typedef __bf16 bf16x8 __attribute__((ext_vector_type(8)));
typedef __bf16 bf16x4 __attribute__((ext_vector_type(4)));
typedef float f32x4 __attribute__((ext_vector_type(4)));
typedef unsigned char u8;

__device__ __forceinline__ void gl2lds16(const void* g, void* l) {
    __builtin_amdgcn_global_load_lds(
        (const __attribute__((address_space(1))) void*)g,
        (__attribute__((address_space(3))) void*)l,
        16, 0, 0);
}

// pack 4 floats (scaled) -> 4 fp8 e4m3 bytes
__device__ __forceinline__ unsigned pk8(float4 v, float s) {
    int lo = __builtin_amdgcn_cvt_pk_fp8_f32(v.x * s, v.y * s, 0, false);
    int r  = __builtin_amdgcn_cvt_pk_fp8_f32(v.z * s, v.w * s, lo, true);
    return (unsigned)r;
}

// K1: per-row L2 norm -> bf16 copy (for tail) + fp8 e4m3 copy scaled x16 (for gemm);
// zero rsum. Block 0 additionally computes class stats and zeroes out.
__global__ __launch_bounds__(256) void k_prep(const float* __restrict__ X,
                                              bf16* __restrict__ Xn,
                                              u8* __restrict__ Xq,
                                              float* __restrict__ rsum,
                                              const int* __restrict__ y,
                                              int* __restrict__ cnt,
                                              int* __restrict__ mn1,
                                              int* __restrict__ mn2,
                                              float* __restrict__ out) {
    int w = threadIdx.x >> 6, lane = threadIdx.x & 63;
    int row = blockIdx.x * 4 + w;
    const float* xr = X + (size_t)row * DD;
    float4 v[4];
    float ss = 0.f;
#pragma unroll
    for (int c = 0; c < 4; ++c) {
        v[c] = *(const float4*)(xr + c * 256 + lane * 4);
        ss += v[c].x * v[c].x + v[c].y * v[c].y + v[c].z * v[c].z + v[c].w * v[c].w;
    }
#pragma unroll
    for (int m = 1; m < 64; m <<= 1) ss += __shfl_xor(ss, m, 64);
    float rn = 1.f / fmaxf(sqrtf(ss), EPSV);
    if (lane == 0) rsum[row] = 0.f;
#pragma unroll
    for (int c = 0; c < 4; ++c) {
        bf16x4 o;
        o.x = (bf16)(v[c].x * rn);
        o.y = (bf16)(v[c].y * rn);
        o.z = (bf16)(v[c].z * rn);
        o.w = (bf16)(v[c].w * rn);
        *(bf16x4*)(Xn + (size_t)row * DD + c * 256 + lane * 4) = o;
        *(unsigned*)(Xq + (size_t)row * DD + c * 256 + lane * 4) = pk8(v[c], rn * 16.f);
    }

    if (blockIdx.x == 0) {
        __shared__ int sc[NCLS], s1[NCLS], s2[NCLS];
        int t = threadIdx.x;
        if (t < NCLS) { sc[t] = 0; s1[t] = 0x7fffffff; s2[t] = 0x7fffffff; }
        __syncthreads();
        int yv[16];
#pragma unroll
        for (int k = 0; k < 16; ++k) {
            int i = k * 256 + t;
            yv[k] = y[i];
            atomicAdd(&sc[yv[k]], 1);
            atomicMin(&s1[yv[k]], i);
        }
        __syncthreads();
#pragma unroll
        for (int k = 0; k < 16; ++k) {
            int i = k * 256 + t;
            if (s1[yv[k]] != i) atomicMin(&s2[yv[k]], i);
        }
        __syncthreads();
        if (t < NCLS) { cnt[t] = sc[t]; mn1[t] = s1[t]; mn2[t] = s2[t]; }
        if (t == 0) out[0] = 0.f;
    }
}

// K2: upper-triangle 128x128 tiles, fp8 e4m3 MFMA, BK=64 (16 stages), 16 KB LDS.
// acc = 256*cos. Off-diag tiles also col-reduce (symmetry).
__global__ __launch_bounds__(256) void k_gemm(const u8* __restrict__ Xq,
                                              const int* __restrict__ y,
                                              float* __restrict__ rowsum) {
    __shared__ __align__(16) u8 As[128 * 64];
    __shared__ __align__(16) u8 Bs[128 * 64];
    __shared__ int yA[128], yB[128];

    // decode linear block id -> (bi, bj), bi <= bj
    int id = blockIdx.x;
    float ff = sqrtf((float)(8 * id + 1));
    int bj = (int)((ff - 1.f) * 0.5f);
    if (bj * (bj + 1) / 2 > id) bj--;
    if ((bj + 1) * (bj + 2) / 2 <= id) bj++;
    int bi = id - bj * (bj + 1) / 2;
    const int rowA0 = bi * 128;
    const int rowB0 = bj * 128;
    const bool diag = (bi == bj);

    const int tid = threadIdx.x;
    if (tid < 128) yA[tid] = y[rowA0 + tid];
    else           yB[tid - 128] = y[rowB0 + tid - 128];

    const int lane = tid & 63;
    const int w = tid >> 6;
    const int wm = w & 1, wn = w >> 1;     // 2x2 waves -> each wave 64x64
    const int lr = lane >> 4, lc = lane & 15;

    f32x4 acc[4][4];
#pragma unroll
    for (int i = 0; i < 4; ++i)
#pragma unroll
        for (int j = 0; j < 4; ++j) acc[i][j] = (f32x4){0.f, 0.f, 0.f, 0.f};

    // staging: 512 slots of 16B per tile; slot m: row=m>>2, pair b=m&3,
    // global 16B-pair a = b ^ ((row>>1)&3)  (granule-pair XOR swizzle)
    const u8* gA[2]; const u8* gB[2]; u8* lA[2]; u8* lB[2];
#pragma unroll
    for (int q = 0; q < 2; ++q) {
        int m = q * 256 + tid;
        int row = m >> 2;
        int a = (m & 3) ^ ((row >> 1) & 3);
        gA[q] = Xq + (size_t)(rowA0 + row) * DD + a * 16;
        gB[q] = Xq + (size_t)(rowB0 + row) * DD + a * 16;
        lA[q] = As + m * 16;
        lB[q] = Bs + m * 16;
    }

    const int psw = 2 * ((lc >> 1) & 3);   // read-side pos swizzle (bits 1-2)

    for (int k0 = 0; k0 < DD; k0 += 64) {
        __syncthreads();
#pragma unroll
        for (int q = 0; q < 2; ++q) {
            gl2lds16(gA[q] + k0, lA[q]);
            gl2lds16(gB[q] + k0, lB[q]);
        }
        __syncthreads();

#pragma unroll
        for (int ks = 0; ks < 2; ++ks) {
            int pos = (ks * 4 + lr) ^ psw;   // 8B granule within 64B row
            long af[4], bfr[4];
#pragma unroll
            for (int mt = 0; mt < 4; ++mt)
                af[mt] = *(const long*)(As + (wm * 64 + mt * 16 + lc) * 64 + pos * 8);
#pragma unroll
            for (int nt = 0; nt < 4; ++nt)
                bfr[nt] = *(const long*)(Bs + (wn * 64 + nt * 16 + lc) * 64 + pos * 8);
#pragma unroll
            for (int mt = 0; mt < 4; ++mt)
#pragma unroll
                for (int nt = 0; nt < 4; ++nt)
                    acc[mt][nt] = __builtin_amdgcn_mfma_f32_16x16x32_fp8_fp8(
                        af[mt], bfr[nt], acc[mt][nt], 0, 0, 0);
        }
    }

    // Epilogue: cos = acc/256; S=(cos+1)*0.25; mask same-class; row+col exp-sums.
    int ycol[4];
#pragma unroll
    for (int nt = 0; nt < 4; ++nt) ycol[nt] = yB[wn * 64 + nt * 16 + lc];
    float colacc[4] = {0.f, 0.f, 0.f, 0.f};
#pragma unroll
    for (int mt = 0; mt < 4; ++mt) {
#pragma unroll
        for (int rr = 0; rr < 4; ++rr) {
            int rloc = wm * 64 + mt * 16 + lr * 4 + rr;  // C row = (lane>>4)*4+reg
            int yrow = yA[rloc];
            float s = 0.f;
#pragma unroll
            for (int nt = 0; nt < 4; ++nt) {
                float Sv = acc[mt][nt][rr] * (0.25f / 256.f) + 0.25f;
                float e = (ycol[nt] != yrow) ? __expf(Sv) : 0.f;
                s += e;
                colacc[nt] += e;
            }
            s += __shfl_xor(s, 1, 16);
            s += __shfl_xor(s, 2, 16);
            s += __shfl_xor(s, 4, 16);
            s += __shfl_xor(s, 8, 16);
            if (lc == 0) atomicAdd(&rowsum[rowA0 + rloc], s);
        }
    }
    if (!diag) {
#pragma unroll
        for (int nt = 0; nt < 4; ++nt) {
            float cs = colacc[nt];
            cs += __shfl_xor(cs, 16, 64);
            cs += __shfl_xor(cs, 32, 64);
            if (lane < 16) atomicAdd(&rowsum[rowB0 + wn * 64 + nt * 16 + lane], cs);
        }
    }
}

// K3: fused posval + finalize. One wave per row.
__global__ __launch_bounds__(256) void k_tail(const bf16* __restrict__ Xn,
                                              const int* __restrict__ y,
                                              const int* __restrict__ cnt,
                                              const int* __restrict__ mn1,
                                              const int* __restrict__ mn2,
                                              const float* __restrict__ rowsum,
                                              float* __restrict__ out) {
    int w = threadIdx.x >> 6, lane = threadIdx.x & 63;
    int i = blockIdx.x * 4 + w;
    int c = y[i];
    int cc = cnt[c];
    float pv = 0.f;
    if (cc >= 2) {
        int fp = (mn1[c] == i) ? mn2[c] : mn1[c];
        const bf16* xi = Xn + (size_t)i * DD;
        const bf16* xf = Xn + (size_t)fp * DD;
        float dot = 0.f;
#pragma unroll
        for (int q = 0; q < 2; ++q) {
            bf16x8 a = *(const bf16x8*)(xi + q * 512 + lane * 8);
            bf16x8 b = *(const bf16x8*)(xf + q * 512 + lane * 8);
#pragma unroll
            for (int e = 0; e < 8; ++e) dot += (float)a[e] * (float)b[e];
        }
#pragma unroll
        for (int m = 1; m < 64; m <<= 1) dot += __shfl_xor(dot, m, 64);
        pv = (dot + 1.f) * (0.5f * TAU);
    }
    float contrib = logf(rowsum[i] + __expf(pv) + (float)(NN - 2 + cc)) - pv;
    __shared__ float wsum[4];
    if (lane == 0) wsum[w] = contrib;
    __syncthreads();
    if (threadIdx.x == 0)
        atomicAdd(out, (wsum[0] + wsum[1] + wsum[2] + wsum[3]) * (1.f / (float)NN));
}

extern "C" void kernel_launch(void* const* d_in, const int* in_sizes, int n_in,
                              void* d_out, int out_size, void* d_ws, size_t ws_size,
                              hipStream_t stream) {
    const float* X = (const float*)d_in[0];
    const int* y = (const int*)d_in[1];
    float* out = (float*)d_out;

    char* ws = (char*)d_ws;
    bf16* Xn    = (bf16*)ws;                                   // 8 MB
    u8*   Xq    = (u8*)(ws + 8 * 1024 * 1024);                 // 4 MB
    float* rsum = (float*)(ws + 12 * 1024 * 1024);             // 16 KB
    int* cnt    = (int*)(ws + 12 * 1024 * 1024 + 16 * 1024);
    int* mn1    = (int*)(ws + 12 * 1024 * 1024 + 16 * 1024 + 512);
    int* mn2    = (int*)(ws + 12 * 1024 * 1024 + 16 * 1024 + 1024);

    k_prep<<<dim3(NN / 4), 256, 0, stream>>>(X, Xn, Xq, rsum, y, cnt, mn1, mn2, out);
    k_gemm<<<dim3(528), 256, 0, stream>>>(Xq, y, rsum);
    k_tail<<<dim3(NN / 4), 256, 0, stream>>>(Xn, y, cnt, mn1, mn2, rsum, out);
}

// Round 7
// 115.673 us; speedup vs baseline: 1.1022x; 1.0571x over previous
//
#include <hip/hip_runtime.h>
#include <hip/hip_bf16.h>
#include <math.h>

#define NN 4096
#define DD 1024
#define NCLS 128
#define TAU 0.5f
#define EPSV 1e-8f

typedef __bf16 bf16;
typedef __bf16 bf16x8 __attribute__((ext_vector_type(8)));
typedef __bf16 bf16x4 __attribute__((ext_vector_type(4)));
typedef float f32x4 __attribute__((ext_vector_type(4)));

__device__ __forceinline__ void gl2lds16(const void* g, void* l) {
    __builtin_amdgcn_global_load_lds(
        (const __attribute__((address_space(1))) void*)g,
        (__attribute__((address_space(3))) void*)l,
        16, 0, 0);
}

// K1: per-row L2 norm -> normalized bf16 copy; zero rsum. One wave per row.
__global__ __launch_bounds__(256) void k_norm_cast(const float* __restrict__ X,
                                                   bf16* __restrict__ Xn,
                                                   float* __restrict__ rsum) {
    int w = threadIdx.x >> 6, lane = threadIdx.x & 63;
    int row = blockIdx.x * 4 + w;
    const float* xr = X + (size_t)row * DD;
    float4 v[4];
    float ss = 0.f;
#pragma unroll
    for (int c = 0; c < 4; ++c) {
        v[c] = *(const float4*)(xr + c * 256 + lane * 4);
        ss += v[c].x * v[c].x + v[c].y * v[c].y + v[c].z * v[c].z + v[c].w * v[c].w;
    }
#pragma unroll
    for (int m = 1; m < 64; m <<= 1) ss += __shfl_xor(ss, m, 64);
    float rn = 1.f / fmaxf(sqrtf(ss), EPSV);
    if (lane == 0) rsum[row] = 0.f;
#pragma unroll
    for (int c = 0; c < 4; ++c) {
        bf16x4 o;
        o.x = (bf16)(v[c].x * rn);
        o.y = (bf16)(v[c].y * rn);
        o.z = (bf16)(v[c].z * rn);
        o.w = (bf16)(v[c].w * rn);
        *(bf16x4*)(Xn + (size_t)row * DD + c * 256 + lane * 4) = o;
    }
}

// K2: fused class stats in one workgroup (self-initializing, LDS atomics):
// cnt[c], mn1[c]=min index, mn2[c]=second-min index. Thread 0 zeroes out.
__global__ __launch_bounds__(1024) void k_classes(const int* __restrict__ y,
                                                  int* __restrict__ cnt,
                                                  int* __restrict__ mn1,
                                                  int* __restrict__ mn2,
                                                  float* __restrict__ out) {
    __shared__ int sc[NCLS], s1[NCLS], s2[NCLS];
    int t = threadIdx.x;
    if (t < NCLS) { sc[t] = 0; s1[t] = 0x7fffffff; s2[t] = 0x7fffffff; }
    __syncthreads();
    int yv[4];
#pragma unroll
    for (int k = 0; k < 4; ++k) {
        int i = t + k * 1024;
        yv[k] = y[i];
        atomicAdd(&sc[yv[k]], 1);
        atomicMin(&s1[yv[k]], i);
    }
    __syncthreads();
#pragma unroll
    for (int k = 0; k < 4; ++k) {
        int i = t + k * 1024;
        if (s1[yv[k]] != i) atomicMin(&s2[yv[k]], i);
    }
    __syncthreads();
    if (t < NCLS) { cnt[t] = sc[t]; mn1[t] = s1[t]; mn2[t] = s2[t]; }
    if (t == 0) out[0] = 0.f;
}

// K3: upper-triangle 128x128-tile bf16 MFMA gram, BK=32, fused exp/mask epilogue.
// Off-diagonal tiles contribute to rowsum via row-reduce AND col-reduce (symmetry).
// (Exact structure that measured fastest: R3.)
__global__ __launch_bounds__(256) void k_gemm(const bf16* __restrict__ Xn,
                                              const int* __restrict__ y,
                                              float* __restrict__ rowsum) {
    __shared__ __align__(16) bf16 As[128 * 32];
    __shared__ __align__(16) bf16 Bs[128 * 32];
    __shared__ int yA[128], yB[128];

    // decode linear block id -> (bi, bj), bi <= bj
    int id = blockIdx.x;
    float ff = sqrtf((float)(8 * id + 1));
    int bj = (int)((ff - 1.f) * 0.5f);
    if (bj * (bj + 1) / 2 > id) bj--;
    if ((bj + 1) * (bj + 2) / 2 <= id) bj++;
    int bi = id - bj * (bj + 1) / 2;
    const int rowA0 = bi * 128;
    const int rowB0 = bj * 128;
    const bool diag = (bi == bj);

    const int tid = threadIdx.x;
    if (tid < 128) yA[tid] = y[rowA0 + tid];
    else           yB[tid - 128] = y[rowB0 + tid - 128];

    const int lane = tid & 63;
    const int w = tid >> 6;
    const int wm = w & 1, wn = w >> 1;     // 2x2 waves -> each wave 64x64
    const int lr = lane >> 4, lc = lane & 15;

    f32x4 acc[4][4];
#pragma unroll
    for (int i = 0; i < 4; ++i)
#pragma unroll
        for (int j = 0; j < 4; ++j) acc[i][j] = (f32x4){0.f, 0.f, 0.f, 0.f};

    // staging with k-slot XOR swizzle: slot g of row r holds k-group g^((r>>1)&3)
    const int r = tid >> 2;
    const int g = tid & 3;
    const int kg = g ^ ((r >> 1) & 3);
    const bf16* gA0 = Xn + (size_t)(rowA0 + r) * DD + kg * 8;
    const bf16* gA1 = gA0 + (size_t)64 * DD;
    const bf16* gB0 = Xn + (size_t)(rowB0 + r) * DD + kg * 8;
    const bf16* gB1 = gB0 + (size_t)64 * DD;
    bf16* lA0 = As + tid * 8;
    bf16* lA1 = As + 64 * 32 + tid * 8;
    bf16* lB0 = Bs + tid * 8;
    bf16* lB1 = Bs + 64 * 32 + tid * 8;

    const int sw = (lc >> 1) & 3;   // read-side swizzle

    for (int k0 = 0; k0 < DD; k0 += 32) {
        __syncthreads();
        gl2lds16(gA0 + k0, lA0);
        gl2lds16(gA1 + k0, lA1);
        gl2lds16(gB0 + k0, lB0);
        gl2lds16(gB1 + k0, lB1);
        __syncthreads();

        bf16x8 af[4], bfr[4];
#pragma unroll
        for (int mt = 0; mt < 4; ++mt)
            af[mt] = *(const bf16x8*)(As + (wm * 64 + mt * 16 + lc) * 32 + ((lr ^ sw) * 8));
#pragma unroll
        for (int nt = 0; nt < 4; ++nt)
            bfr[nt] = *(const bf16x8*)(Bs + (wn * 64 + nt * 16 + lc) * 32 + ((lr ^ sw) * 8));
#pragma unroll
        for (int mt = 0; mt < 4; ++mt)
#pragma unroll
            for (int nt = 0; nt < 4; ++nt)
                acc[mt][nt] = __builtin_amdgcn_mfma_f32_16x16x32_bf16(
                    af[mt], bfr[nt], acc[mt][nt], 0, 0, 0);
    }

    // Epilogue: S=(c+1)*0.25; mask same-class (incl. diagonal); row+col exp-sums.
    int ycol[4];
#pragma unroll
    for (int nt = 0; nt < 4; ++nt) ycol[nt] = yB[wn * 64 + nt * 16 + lc];
    float colacc[4] = {0.f, 0.f, 0.f, 0.f};
#pragma unroll
    for (int mt = 0; mt < 4; ++mt) {
#pragma unroll
        for (int rr = 0; rr < 4; ++rr) {
            int rloc = wm * 64 + mt * 16 + lr * 4 + rr;  // C row = (lane>>4)*4+reg
            int yrow = yA[rloc];
            float s = 0.f;
#pragma unroll
            for (int nt = 0; nt < 4; ++nt) {
                float Sv = (acc[mt][nt][rr] + 1.f) * (0.5f * TAU);
                float e = (ycol[nt] != yrow) ? __expf(Sv) : 0.f;
                s += e;
                colacc[nt] += e;
            }
            s += __shfl_xor(s, 1, 16);
            s += __shfl_xor(s, 2, 16);
            s += __shfl_xor(s, 4, 16);
            s += __shfl_xor(s, 8, 16);
            if (lc == 0) atomicAdd(&rowsum[rowA0 + rloc], s);
        }
    }
    if (!diag) {
#pragma unroll
        for (int nt = 0; nt < 4; ++nt) {
            float cs = colacc[nt];
            cs += __shfl_xor(cs, 16, 64);
            cs += __shfl_xor(cs, 32, 64);
            if (lane < 16) atomicAdd(&rowsum[rowB0 + wn * 64 + nt * 16 + lane], cs);
        }
    }
}

// K4: fused posval + finalize. One wave per row; atomicAdd into out.
__global__ __launch_bounds__(256) void k_tail(const bf16* __restrict__ Xn,
                                              const int* __restrict__ y,
                                              const int* __restrict__ cnt,
                                              const int* __restrict__ mn1,
                                              const int* __restrict__ mn2,
                                              const float* __restrict__ rowsum,
                                              float* __restrict__ out) {
    int w = threadIdx.x >> 6, lane = threadIdx.x & 63;
    int i = blockIdx.x * 4 + w;
    int c = y[i];
    int cc = cnt[c];
    float pv = 0.f;
    if (cc >= 2) {
        int fp = (mn1[c] == i) ? mn2[c] : mn1[c];
        const bf16* xi = Xn + (size_t)i * DD;
        const bf16* xf = Xn + (size_t)fp * DD;
        float dot = 0.f;
#pragma unroll
        for (int q = 0; q < 2; ++q) {
            bf16x8 a = *(const bf16x8*)(xi + q * 512 + lane * 8);
            bf16x8 b = *(const bf16x8*)(xf + q * 512 + lane * 8);
#pragma unroll
            for (int e = 0; e < 8; ++e) dot += (float)a[e] * (float)b[e];
        }
#pragma unroll
        for (int m = 1; m < 64; m <<= 1) dot += __shfl_xor(dot, m, 64);
        pv = (dot + 1.f) * (0.5f * TAU);
    }
    float contrib = logf(rowsum[i] + __expf(pv) + (float)(NN - 2 + cc)) - pv;
    __shared__ float wsum[4];
    if (lane == 0) wsum[w] = contrib;
    __syncthreads();
    if (threadIdx.x == 0)
        atomicAdd(out, (wsum[0] + wsum[1] + wsum[2] + wsum[3]) * (1.f / (float)NN));
}

extern "C" void kernel_launch(void* const* d_in, const int* in_sizes, int n_in,
                              void* d_out, int out_size, void* d_ws, size_t ws_size,
                              hipStream_t stream) {
    const float* X = (const float*)d_in[0];
    const int* y = (const int*)d_in[1];
    float* out = (float*)d_out;

    char* ws = (char*)d_ws;
    bf16* Xn    = (bf16*)ws;                                  // 8 MB
    float* rsum = (float*)(ws + 8 * 1024 * 1024);             // 16 KB
    int* cnt    = (int*)(ws + 8 * 1024 * 1024 + 16 * 1024);
    int* mn1    = (int*)(ws + 8 * 1024 * 1024 + 16 * 1024 + 512);
    int* mn2    = (int*)(ws + 8 * 1024 * 1024 + 16 * 1024 + 1024);

    k_norm_cast<<<dim3(NN / 4), 256, 0, stream>>>(X, Xn, rsum);
    k_classes<<<dim3(1), 1024, 0, stream>>>(y, cnt, mn1, mn2, out);
    k_gemm<<<dim3(528), 256, 0, stream>>>(Xn, y, rsum);
    k_tail<<<dim3(NN / 4), 256, 0, stream>>>(Xn, y, cnt, mn1, mn2, rsum, out);
}